// Round 7
// baseline (315.200 us; speedup 1.0000x reference)
//
#include <hip/hip_runtime.h>
#include <hip/hip_bf16.h>

// GQA: B=2, T=2048, C=2048, H=32, KV=8, D=64, n_rep=4, causal, RoPE base 1e4.
// Round 13 (base = round-11 green, 69.2us flash): V LEAVES THE LDS PATH.
// V fragments are loaded per-lane global->regs at tile start (vt is 4MB,
// L2/L3-resident; ~500cyc of S-MFMA+softmax hides the latency) and consumed
// in PV. K staging/dbuf/barriers unchanged. Effects: LDS traffic halved
// (8 ds_read_b128/tile instead of 16), barrier vmcnt-drain covers 2 staging
// loads/thread instead of 4, LDS 32KB->16KB. No sync-structure or asm changes.
// Fragment equivalence verified: global addr (ds*16+l15)*T + kt*64+ks*32+g*8
// == old swizzled-LDS read content (XOR cancels against gload_lds source swz).

typedef __hip_bfloat16 bf16_t;
typedef __bf16 bf16x8 __attribute__((ext_vector_type(8)));
typedef float f32x4 __attribute__((ext_vector_type(4)));

#define AS1 __attribute__((address_space(1)))
#define AS3 __attribute__((address_space(3)))

__device__ __forceinline__ void gload_lds16(const void* g, void* l) {
  __builtin_amdgcn_global_load_lds((const AS1 unsigned int*)g,
                                   (AS3 unsigned int*)l, 16, 0, 0);
}

__device__ __forceinline__ float fast_exp2(float x) {
#if __has_builtin(__builtin_amdgcn_exp2f)
  return __builtin_amdgcn_exp2f(x);
#else
  return exp2f(x);
#endif
}

__device__ __forceinline__ unsigned int pack_bf16_rnd(unsigned int u0, unsigned int u1) {
  u0 += 0x8000u; u1 += 0x8000u;
#if __has_builtin(__builtin_amdgcn_perm)
  return __builtin_amdgcn_perm(u1, u0, 0x07060302u);
#else
  return (u1 & 0xffff0000u) | (u0 >> 16);
#endif
}

// v_permlane32_swap_b32 a,b : a' = [a.lo | b.lo], b' = [a.hi | b.hi]  (32-lane halves)
// v_permlane16_swap_b32 a,b : a' = [a0 b0 a2 b2], b' = [a1 b1 a3 b3]  (16-lane rows)
__device__ __forceinline__ void permlane32_swap(unsigned& a, unsigned& b) {
  asm volatile("v_permlane32_swap_b32 %0, %1" : "+v"(a), "+v"(b));
}
__device__ __forceinline__ void permlane16_swap(unsigned& a, unsigned& b) {
  asm volatile("v_permlane16_swap_b32 %0, %1" : "+v"(a), "+v"(b));
}

__device__ __forceinline__ void store_out(float* p, float v) { *p = v; }
__device__ __forceinline__ void store_out(bf16_t* p, float v) { *p = __float2bfloat16(v); }

// ---------------- prep: cast x + transpose/cast all 4 weights, one launch ----------------
__global__ void prep(const float* __restrict__ x, const float* __restrict__ Wq,
                     const float* __restrict__ Wk, const float* __restrict__ Wv,
                     const float* __restrict__ Wo, bf16_t* __restrict__ xb,
                     bf16_t* __restrict__ wqkvt, bf16_t* __restrict__ wot) {
  const int bid = blockIdx.x, tid = threadIdx.x;
  if (bid < 2048) {
#pragma unroll
    for (int k = 0; k < 4; ++k) {
      int i = bid * 1024 + k * 256 + tid;
      float4 v = ((const float4*)x)[i];
      bf16_t o[4] = {__float2bfloat16(v.x), __float2bfloat16(v.y),
                     __float2bfloat16(v.z), __float2bfloat16(v.w)};
      ((ushort4*)xb)[i] = *(ushort4*)o;
    }
    return;
  }
  const float* W; bf16_t* dst; int ncols, bx, by;
  if (bid < 6144)       { int l = bid - 2048;  W = Wq; dst = wqkvt;               ncols = 2048; bx = l & 63; by = l >> 6; }
  else if (bid < 10240) { int l = bid - 6144;  W = Wo; dst = wot;                 ncols = 2048; bx = l & 63; by = l >> 6; }
  else if (bid < 11264) { int l = bid - 10240; W = Wk; dst = wqkvt + 2048L * 2048; ncols = 512; bx = l & 15; by = l >> 4; }
  else                  { int l = bid - 11264; W = Wv; dst = wqkvt + 2560L * 2048; ncols = 512; bx = l & 15; by = l >> 4; }
  __shared__ float tile[32][33];
  const int tx = tid & 31, ty = tid >> 5;
  const int n0 = bx * 32, k0 = by * 32;
#pragma unroll
  for (int i = 0; i < 4; ++i)
    tile[ty + 8 * i][tx] = W[(long)(k0 + ty + 8 * i) * ncols + n0 + tx];
  __syncthreads();
#pragma unroll
  for (int i = 0; i < 4; ++i)
    dst[(long)(n0 + ty + 8 * i) * 2048 + k0 + tx] = __float2bfloat16(tile[tx][ty + 8 * i]);
}

// ---------------- GEMM: C[M][N] = A[M][K] * Bt[N][K]^T, bf16 in, fp32 acc ----------------
// MODE 0: plain store. MODE 1 (QKV): fused epilogue —
//   q cols (<2048):   RoPE on fp32 acc, pre-scale 0.125*log2(e), bf16 store
//   k cols (<2560):   RoPE on fp32 acc, bf16 store
//   v cols (>=2560):  no rope; store transposed into vt[(b*8+kv)*64+d][T]
template <typename OutT, int MODE>
__global__ __launch_bounds__(256, 3)
void gemm_bt(const bf16_t* __restrict__ A, const bf16_t* __restrict__ Bt,
             OutT* __restrict__ C, int M, int N, int K, bf16_t* __restrict__ vt) {
  __shared__ __align__(16) bf16_t As[128 * 64];
  __shared__ __align__(16) bf16_t Bs[128 * 64];
  const int tid = threadIdx.x;
  const int wave = tid >> 6, lane = tid & 63, g = lane >> 4, l15 = lane & 15;
  const int m0 = blockIdx.y * 128, n0 = blockIdx.x * 128;
  const int mw = (wave >> 1) * 64, nw = (wave & 1) * 64;
  const bf16_t* Ab = A + (long)m0 * K;
  const bf16_t* Bb = Bt + (long)n0 * K;
  f32x4 acc[4][4] = {};
  const int nkt = K >> 6;
  for (int kt = 0; kt < nkt; ++kt) {
    __syncthreads();
#pragma unroll
    for (int i = 0; i < 4; ++i) {
      int c = i * 256 + tid;
      int row = c >> 3, pos = c & 7;
      int gcol = ((pos ^ (row & 7)) * 8);
      gload_lds16(Ab + (long)row * K + kt * 64 + gcol, &As[c * 8]);
      gload_lds16(Bb + (long)row * K + kt * 64 + gcol, &Bs[c * 8]);
    }
    __syncthreads();
#pragma unroll
    for (int ks = 0; ks < 2; ++ks) {
      bf16x8 af[4], bq[4];
#pragma unroll
      for (int i = 0; i < 4; ++i) {
        int pos = ((ks * 4 + g) ^ (l15 & 7)) * 8;
        af[i] = *(const bf16x8*)&As[(mw + i * 16 + l15) * 64 + pos];
        bq[i] = *(const bf16x8*)&Bs[(nw + i * 16 + l15) * 64 + pos];
      }
#pragma unroll
      for (int i = 0; i < 4; ++i)
#pragma unroll
        for (int j = 0; j < 4; ++j)
          acc[i][j] = __builtin_amdgcn_mfma_f32_16x16x32_bf16(af[i], bq[j], acc[i][j], 0, 0, 0);
    }
  }

  if (MODE == 1) {
    const int cnb = n0 + nw;                 // wave's head base col (mult of 64)
    if (cnb >= 2560) {
      // ---- V: store transposed into vt[((b*8+kv)*64 + d)*2048 + t] ----
      const int kv = (cnb - 2560) >> 6;
      const int bb = m0 >> 11;
#pragma unroll
      for (int i = 0; i < 4; ++i) {
        const int t0 = (m0 & 2047) + mw + i * 16 + g * 4;
#pragma unroll
        for (int j = 0; j < 4; ++j) {
          const int d = j * 16 + l15;
          bf16_t o4[4];
#pragma unroll
          for (int ii = 0; ii < 4; ++ii) o4[ii] = __float2bfloat16(acc[i][j][ii]);
          *(ushort4*)&vt[((long)((bb * 8 + kv) * 64 + d)) * 2048 + t0] = *(ushort4*)o4;
        }
      }
    } else {
      // ---- Q/K: RoPE in-register (pair (d, d+32) = acc[i][jp] / acc[i][jp+2]) ----
      const float sc = (cnb < 2048) ? 0.18033688011112043f : 1.0f;  // 0.125*log2(e) for q
#pragma unroll
      for (int jp = 0; jp < 2; ++jp) {
        const int d = jp * 16 + l15;
        const float invf = exp2f(-(float)d * 0.4152410118074032f);  // log2(10000)/32
        const int cn = cnb + jp * 16 + l15;
#pragma unroll
        for (int i = 0; i < 4; ++i) {
          const int r0 = m0 + mw + i * 16 + g * 4;
#pragma unroll
          for (int ii = 0; ii < 4; ++ii) {
            const int t = (r0 + ii) & 2047;
            float ang = (float)t * invf;
            float rev = ang * 0.15915494309189535f;
            float fr = (rev - rintf(rev)) * 6.283185307179586f;  // [-pi, pi]
            float sv = __sinf(fr), cv = __cosf(fr);
            float x1 = acc[i][jp][ii], x2 = acc[i][jp + 2][ii];
            store_out(&C[(long)(r0 + ii) * N + cn],      (x1 * cv - x2 * sv) * sc);
            store_out(&C[(long)(r0 + ii) * N + cn + 32], (x1 * sv + x2 * cv) * sc);
          }
        }
      }
    }
  } else {
#pragma unroll
    for (int i = 0; i < 4; ++i)
#pragma unroll
      for (int j = 0; j < 4; ++j) {
        int r = m0 + mw + i * 16 + g * 4;
        int cn = n0 + nw + j * 16 + l15;
#pragma unroll
        for (int ii = 0; ii < 4; ++ii)
          store_out(&C[(long)(r + ii) * N + cn], acc[i][j][ii]);
      }
  }
}

// ---------------- Flash attention: 64-key tiles, K-dbuf in LDS, V direct global->reg ----------------
// qt0 = (x<8)?(15-x):(x-8); flipped by (h>>4)&1 so a CU's 4 blocks (same x,
// h differing by 16, both b) get {qt, 15-qt} x2 -> 68 k-tiles per CU, uniform.
// LDS: Ks 2x8K = 16384 B. P in registers (permlane relayout); V in registers
// (per-lane global b128, issued at tile start, consumed after S+softmax).
__global__ __launch_bounds__(256, 4)
void flash_attn(const bf16_t* __restrict__ qkv, const bf16_t* __restrict__ vt,
                bf16_t* __restrict__ y) {
  constexpr int T = 2048, LDQ = 3072;
  __shared__ __align__(16) bf16_t Ks[2][64 * 64];   // [kk][d], chunk-swizzled
  const int tid = threadIdx.x, wave = tid >> 6, lane = tid & 63, g = lane >> 4, l15 = lane & 15;
  const int j = blockIdx.x;
  const int h = blockIdx.y, b = blockIdx.z;
  const int qt0 = (j < 8) ? (15 - j) : (j - 8);
  const int qt = ((h >> 4) & 1) ? (15 - qt0) : qt0;   // per-CU balance (see header)
  const int kvh = h >> 2;
  const bf16_t* qbase = qkv + (long)(b * T + qt * 128) * LDQ + h * 64;
  const bf16_t* kbase = qkv + (long)(b * T) * LDQ + 2048 + kvh * 64;
  const bf16_t* vbase = vt + (long)((b * 8 + kvh) * 64) * T;

  // Q fragments (B-operand layout: n=q=l15, kdim=g*8+jj)
  bf16x8 qf[2][2];
#pragma unroll
  for (int ms = 0; ms < 2; ++ms)
#pragma unroll
    for (int hh = 0; hh < 2; ++hh)
      qf[ms][hh] = *(const bf16x8*)(qbase + (long)(wave * 32 + ms * 16 + l15) * LDQ + hh * 32 + g * 8);

  bf16x8 onef;
#pragma unroll
  for (int i = 0; i < 8; ++i) onef[i] = (__bf16)1.0f;

  f32x4 o[2][4] = {};
  f32x4 lacc[2] = {};
  const f32x4 fz = {0.f, 0.f, 0.f, 0.f};

  // hoisted K-staging addresses: c = i*256+tid, i in {0,1}
  const int c0 = tid, c1 = 256 + tid;
  const int row0 = c0 >> 3, pos0 = c0 & 7, sw0 = ((pos0 ^ (row0 & 7)) * 8);
  const int row1 = c1 >> 3, pos1 = c1 & 7, sw1 = ((pos1 ^ (row1 & 7)) * 8);
  const bf16_t* kp0 = kbase + (long)row0 * LDQ + sw0;
  const bf16_t* kp1 = kbase + (long)row1 * LDQ + sw1;
  const int l0 = c0 * 8, l1 = c1 * 8;

  auto stage = [&](int buf) {
    gload_lds16(kp0, &Ks[buf][l0]);
    gload_lds16(kp1, &Ks[buf][l1]);
    kp0 += 64 * LDQ; kp1 += 64 * LDQ;
  };

  // per-lane V base: fragment (ks,ds) of tile kt lives at
  //   vW + (ds*16)*T + kt*64 + ks*32   (16B-aligned b128)
  const bf16_t* vW = vbase + (long)l15 * T + g * 8;

  stage(0);
  const int nkt = 2 * qt + 2;
  for (int kt = 0; kt < nkt; ++kt) {
    __syncthreads();               // vmcnt(0) drain precedes barrier: Ks[kt&1] ready
    // V fragments for THIS tile: global -> regs; first use is after all
    // S-MFMAs + softmax of ks=0 (~500 cyc) -> L2 latency hidden.
    bf16x8 vf[2][4];
#pragma unroll
    for (int vks = 0; vks < 2; ++vks)
#pragma unroll
      for (int ds = 0; ds < 4; ++ds)
        vf[vks][ds] = *(const bf16x8*)(vW + (long)(ds * 16) * T + kt * 64 + vks * 32);
    if (kt + 1 < nkt) stage((kt + 1) & 1);
    const bf16_t* Kc = Ks[kt & 1];
    const int dk = kt - 2 * qt;        // >=0 only on the two diagonal tiles
    const bool diag = (dk >= 0);

#pragma unroll
    for (int ks = 0; ks < 2; ++ks) {
      // ---- S^T chunk: rows k = ks*32 + nsl*16 + g*4+ii, cols q = l15 ----
      f32x4 s[2][2];
      __builtin_amdgcn_s_setprio(1);
#pragma unroll
      for (int nsl = 0; nsl < 2; ++nsl) {
        int krow = ks * 32 + nsl * 16 + l15;
        bf16x8 kf0 = *(const bf16x8*)&Kc[krow * 64 + ((g ^ (l15 & 7)) * 8)];
        bf16x8 kf1 = *(const bf16x8*)&Kc[krow * 64 + (((4 + g) ^ (l15 & 7)) * 8)];
#pragma unroll
        for (int ms = 0; ms < 2; ++ms) {
          f32x4 t = __builtin_amdgcn_mfma_f32_16x16x32_bf16(kf0, qf[ms][0], fz, 0, 0, 0);
          s[ms][nsl] = __builtin_amdgcn_mfma_f32_16x16x32_bf16(kf1, qf[ms][1], t, 0, 0, 0);
        }
      }
      __builtin_amdgcn_s_setprio(0);
      // ---- P = exp2(S) (q pre-scaled), mask, pack, permlane relayout (no LDS) ----
      // S^T regs: lane(g,l15) nsl,ii -> P[q=l15(+ms*16)][k = nsl*16+g*4+ii]
      // A-frag:   lane(g,l15) jj     -> P[q=l15(+ms*16)][k = g*8+jj]
      bf16x8 pf[2];
#pragma unroll
      for (int ms = 0; ms < 2; ++ms) {
        unsigned dw[4];
#pragma unroll
        for (int nsl = 0; nsl < 2; ++nsl) {
          unsigned u[4];
#pragma unroll
          for (int ii = 0; ii < 4; ++ii) {
            float p = fast_exp2(s[ms][nsl][ii]);
            if (diag && (dk * 64 + ks * 32 + nsl * 16 + g * 4 + ii >
                         wave * 32 + ms * 16 + l15)) p = 0.f;
            u[ii] = __builtin_bit_cast(unsigned int, p);
          }
          dw[nsl * 2 + 0] = pack_bf16_rnd(u[0], u[1]);   // k = nsl*16+g*4 + {0,1}
          dw[nsl * 2 + 1] = pack_bf16_rnd(u[2], u[3]);   // k = nsl*16+g*4 + {2,3}
        }
        // rows(g) of dw[0],dw[2]: [S0g0..] / [S2g0..]; after 32swap+16swap:
        // dw[0] = [S0g0 S0g2 S2g0 S2g2] = w0, dw[2] = [S0g1 S0g3 S2g1 S2g3] = w2
        permlane32_swap(dw[0], dw[2]);
        permlane16_swap(dw[0], dw[2]);
        permlane32_swap(dw[1], dw[3]);
        permlane16_swap(dw[1], dw[3]);
        uint4 uu = {dw[0], dw[1], dw[2], dw[3]};
        pf[ms] = __builtin_bit_cast(bf16x8, uu);
        lacc[ms] = __builtin_amdgcn_mfma_f32_16x16x32_bf16(pf[ms], onef, lacc[ms], 0, 0, 0);
      }
      // ---- PV chunk (V from registers) ----
      __builtin_amdgcn_s_setprio(1);
#pragma unroll
      for (int ds = 0; ds < 4; ++ds) {
        o[0][ds] = __builtin_amdgcn_mfma_f32_16x16x32_bf16(pf[0], vf[ks][ds], o[0][ds], 0, 0, 0);
        o[1][ds] = __builtin_amdgcn_mfma_f32_16x16x32_bf16(pf[1], vf[ks][ds], o[1][ds], 0, 0, 0);
      }
      __builtin_amdgcn_s_setprio(0);
    }
  }

  // ---- epilogue: normalize, transpose 16x64 halves via LDS (reuse Ks), b128 stores ----
  __syncthreads();                         // all waves done reading Ks
  bf16_t* E = (bf16_t*)&Ks[0][0] + wave * 1152;  // 16*72 = 1152 per wave (4*1152*2B = 9216B <= 16KB)
#pragma unroll
  for (int ms = 0; ms < 2; ++ms) {
    f32x4 linv;
#pragma unroll
    for (int ii = 0; ii < 4; ++ii) linv[ii] = 1.0f / lacc[ms][ii];
#pragma unroll
    for (int ds = 0; ds < 4; ++ds)
#pragma unroll
      for (int ii = 0; ii < 4; ++ii)
        E[(g * 4 + ii) * 72 + ds * 16 + l15] = __float2bfloat16(o[ms][ds][ii] * linv[ii]);
    // wave-private region, in-order DS ops -> no barrier
    bf16x8 r0 = *(const bf16x8*)&E[l15 * 72 + g * 16];
    bf16x8 r1 = *(const bf16x8*)&E[l15 * 72 + g * 16 + 8];
    int q = qt * 128 + wave * 32 + ms * 16 + l15;
    *(bf16x8*)&y[(long)(b * T + q) * 2048 + h * 64 + g * 16] = r0;
    *(bf16x8*)&y[(long)(b * T + q) * 2048 + h * 64 + g * 16 + 8] = r1;
  }
}

extern "C" void kernel_launch(void* const* d_in, const int* in_sizes, int n_in,
                              void* d_out, int out_size, void* d_ws, size_t ws_size,
                              hipStream_t stream) {
  const float* x  = (const float*)d_in[0];
  const float* Wq = (const float*)d_in[1];
  const float* Wk = (const float*)d_in[2];
  const float* Wv = (const float*)d_in[3];
  const float* Wo = (const float*)d_in[4];
  float* out = (float*)d_out;
  char* ws = (char*)d_ws;

  bf16_t* xb    = (bf16_t*)(ws);                                     // 16.78 MB (reused as y)
  bf16_t* wqkvt = (bf16_t*)(ws + 16777216);                          // 12.58 MB
  bf16_t* wot   = (bf16_t*)(ws + 16777216 + 12582912);               // 8.39 MB
  bf16_t* qkvb  = (bf16_t*)(ws + 16777216 + 12582912 + 8388608);     // 25.17 MB
  bf16_t* vtb   = (bf16_t*)(ws + 16777216 + 12582912 + 8388608 + 25165824); // 4.19 MB
  bf16_t* yb = xb;  // x dead after QKV GEMM

  prep<<<12288, 256, 0, stream>>>(x, Wq, Wk, Wv, Wo, xb, wqkvt, wot);
  gemm_bt<bf16_t, 1><<<dim3(24, 32), 256, 0, stream>>>(xb, wqkvt, qkvb, 4096, 3072, 2048, vtb);
  flash_attn<<<dim3(16, 32, 2), 256, 0, stream>>>(qkvb, vtb, yb);
  gemm_bt<float, 0><<<dim3(16, 32), 256, 0, stream>>>(yb, wot, out, 4096, 2048, 2048, nullptr);
}

// Round 8
// 271.060 us; speedup vs baseline: 1.1628x; 1.1628x over previous
//
#include <hip/hip_runtime.h>
#include <hip/hip_bf16.h>

// GQA: B=2, T=2048, C=2048, H=32, KV=8, D=64, n_rep=4, causal, RoPE base 1e4.
// Round 14 (base = round-11 green flash, 69.2us): XCD-aware block remap ONLY.
// Old mapping: XCD = L&7 = j%8 -> every XCD touches all 16 (b,kvh) K/V panels
// (8MB > 4MB L2) -> staging re-fetches from L3/HBM each tile (FETCH 33.8MB vs
// 25.2 compulsory). New decode from L = x + 16y + 512z:
//   c=L&7, s=L>>3, t=s&31, u=s>>5; p=2c+(t&1); b=p>>3, kvh=p&7; h=kvh*4+u;
//   j0=t>>1; qt0=(j0<8)?15-j0:j0-8; qt=(u&1)?15-qt0:qt0.
// Each XCD owns 2 (b,kvh) pairs (1MB K/V, L2-resident). Same-CU blocks
// (L mod 256 equal -> same c,t; u=0..3) get qt,15-qt,qt,15-qt -> 68 tiles/CU,
// balance preserved. Bijection over (b,h,qt) verified. Inner loop, staging,
// barriers, setprio: byte-identical to round-11 green.

typedef __hip_bfloat16 bf16_t;
typedef __bf16 bf16x8 __attribute__((ext_vector_type(8)));
typedef float f32x4 __attribute__((ext_vector_type(4)));

#define AS1 __attribute__((address_space(1)))
#define AS3 __attribute__((address_space(3)))

__device__ __forceinline__ void gload_lds16(const void* g, void* l) {
  __builtin_amdgcn_global_load_lds((const AS1 unsigned int*)g,
                                   (AS3 unsigned int*)l, 16, 0, 0);
}

__device__ __forceinline__ float fast_exp2(float x) {
#if __has_builtin(__builtin_amdgcn_exp2f)
  return __builtin_amdgcn_exp2f(x);
#else
  return exp2f(x);
#endif
}

__device__ __forceinline__ unsigned int pack_bf16_rnd(unsigned int u0, unsigned int u1) {
  u0 += 0x8000u; u1 += 0x8000u;
#if __has_builtin(__builtin_amdgcn_perm)
  return __builtin_amdgcn_perm(u1, u0, 0x07060302u);
#else
  return (u1 & 0xffff0000u) | (u0 >> 16);
#endif
}

// v_permlane32_swap_b32 a,b : a' = [a.lo | b.lo], b' = [a.hi | b.hi]  (32-lane halves)
// v_permlane16_swap_b32 a,b : a' = [a0 b0 a2 b2], b' = [a1 b1 a3 b3]  (16-lane rows)
__device__ __forceinline__ void permlane32_swap(unsigned& a, unsigned& b) {
  asm volatile("v_permlane32_swap_b32 %0, %1" : "+v"(a), "+v"(b));
}
__device__ __forceinline__ void permlane16_swap(unsigned& a, unsigned& b) {
  asm volatile("v_permlane16_swap_b32 %0, %1" : "+v"(a), "+v"(b));
}

__device__ __forceinline__ void store_out(float* p, float v) { *p = v; }
__device__ __forceinline__ void store_out(bf16_t* p, float v) { *p = __float2bfloat16(v); }

// ---------------- prep: cast x + transpose/cast all 4 weights, one launch ----------------
__global__ void prep(const float* __restrict__ x, const float* __restrict__ Wq,
                     const float* __restrict__ Wk, const float* __restrict__ Wv,
                     const float* __restrict__ Wo, bf16_t* __restrict__ xb,
                     bf16_t* __restrict__ wqkvt, bf16_t* __restrict__ wot) {
  const int bid = blockIdx.x, tid = threadIdx.x;
  if (bid < 2048) {
#pragma unroll
    for (int k = 0; k < 4; ++k) {
      int i = bid * 1024 + k * 256 + tid;
      float4 v = ((const float4*)x)[i];
      bf16_t o[4] = {__float2bfloat16(v.x), __float2bfloat16(v.y),
                     __float2bfloat16(v.z), __float2bfloat16(v.w)};
      ((ushort4*)xb)[i] = *(ushort4*)o;
    }
    return;
  }
  const float* W; bf16_t* dst; int ncols, bx, by;
  if (bid < 6144)       { int l = bid - 2048;  W = Wq; dst = wqkvt;               ncols = 2048; bx = l & 63; by = l >> 6; }
  else if (bid < 10240) { int l = bid - 6144;  W = Wo; dst = wot;                 ncols = 2048; bx = l & 63; by = l >> 6; }
  else if (bid < 11264) { int l = bid - 10240; W = Wk; dst = wqkvt + 2048L * 2048; ncols = 512; bx = l & 15; by = l >> 4; }
  else                  { int l = bid - 11264; W = Wv; dst = wqkvt + 2560L * 2048; ncols = 512; bx = l & 15; by = l >> 4; }
  __shared__ float tile[32][33];
  const int tx = tid & 31, ty = tid >> 5;
  const int n0 = bx * 32, k0 = by * 32;
#pragma unroll
  for (int i = 0; i < 4; ++i)
    tile[ty + 8 * i][tx] = W[(long)(k0 + ty + 8 * i) * ncols + n0 + tx];
  __syncthreads();
#pragma unroll
  for (int i = 0; i < 4; ++i)
    dst[(long)(n0 + ty + 8 * i) * 2048 + k0 + tx] = __float2bfloat16(tile[tx][ty + 8 * i]);
}

// ---------------- GEMM: C[M][N] = A[M][K] * Bt[N][K]^T, bf16 in, fp32 acc ----------------
// MODE 0: plain store. MODE 1 (QKV): fused epilogue —
//   q cols (<2048):   RoPE on fp32 acc, pre-scale 0.125*log2(e), bf16 store
//   k cols (<2560):   RoPE on fp32 acc, bf16 store
//   v cols (>=2560):  no rope; store transposed into vt[(b*8+kv)*64+d][T]
template <typename OutT, int MODE>
__global__ __launch_bounds__(256, 3)
void gemm_bt(const bf16_t* __restrict__ A, const bf16_t* __restrict__ Bt,
             OutT* __restrict__ C, int M, int N, int K, bf16_t* __restrict__ vt) {
  __shared__ __align__(16) bf16_t As[128 * 64];
  __shared__ __align__(16) bf16_t Bs[128 * 64];
  const int tid = threadIdx.x;
  const int wave = tid >> 6, lane = tid & 63, g = lane >> 4, l15 = lane & 15;
  const int m0 = blockIdx.y * 128, n0 = blockIdx.x * 128;
  const int mw = (wave >> 1) * 64, nw = (wave & 1) * 64;
  const bf16_t* Ab = A + (long)m0 * K;
  const bf16_t* Bb = Bt + (long)n0 * K;
  f32x4 acc[4][4] = {};
  const int nkt = K >> 6;
  for (int kt = 0; kt < nkt; ++kt) {
    __syncthreads();
#pragma unroll
    for (int i = 0; i < 4; ++i) {
      int c = i * 256 + tid;
      int row = c >> 3, pos = c & 7;
      int gcol = ((pos ^ (row & 7)) * 8);
      gload_lds16(Ab + (long)row * K + kt * 64 + gcol, &As[c * 8]);
      gload_lds16(Bb + (long)row * K + kt * 64 + gcol, &Bs[c * 8]);
    }
    __syncthreads();
#pragma unroll
    for (int ks = 0; ks < 2; ++ks) {
      bf16x8 af[4], bq[4];
#pragma unroll
      for (int i = 0; i < 4; ++i) {
        int pos = ((ks * 4 + g) ^ (l15 & 7)) * 8;
        af[i] = *(const bf16x8*)&As[(mw + i * 16 + l15) * 64 + pos];
        bq[i] = *(const bf16x8*)&Bs[(nw + i * 16 + l15) * 64 + pos];
      }
#pragma unroll
      for (int i = 0; i < 4; ++i)
#pragma unroll
        for (int j = 0; j < 4; ++j)
          acc[i][j] = __builtin_amdgcn_mfma_f32_16x16x32_bf16(af[i], bq[j], acc[i][j], 0, 0, 0);
    }
  }

  if (MODE == 1) {
    const int cnb = n0 + nw;                 // wave's head base col (mult of 64)
    if (cnb >= 2560) {
      // ---- V: store transposed into vt[((b*8+kv)*64 + d)*2048 + t] ----
      const int kv = (cnb - 2560) >> 6;
      const int bb = m0 >> 11;
#pragma unroll
      for (int i = 0; i < 4; ++i) {
        const int t0 = (m0 & 2047) + mw + i * 16 + g * 4;
#pragma unroll
        for (int j = 0; j < 4; ++j) {
          const int d = j * 16 + l15;
          bf16_t o4[4];
#pragma unroll
          for (int ii = 0; ii < 4; ++ii) o4[ii] = __float2bfloat16(acc[i][j][ii]);
          *(ushort4*)&vt[((long)((bb * 8 + kv) * 64 + d)) * 2048 + t0] = *(ushort4*)o4;
        }
      }
    } else {
      // ---- Q/K: RoPE in-register (pair (d, d+32) = acc[i][jp] / acc[i][jp+2]) ----
      const float sc = (cnb < 2048) ? 0.18033688011112043f : 1.0f;  // 0.125*log2(e) for q
#pragma unroll
      for (int jp = 0; jp < 2; ++jp) {
        const int d = jp * 16 + l15;
        const float invf = exp2f(-(float)d * 0.4152410118074032f);  // log2(10000)/32
        const int cn = cnb + jp * 16 + l15;
#pragma unroll
        for (int i = 0; i < 4; ++i) {
          const int r0 = m0 + mw + i * 16 + g * 4;
#pragma unroll
          for (int ii = 0; ii < 4; ++ii) {
            const int t = (r0 + ii) & 2047;
            float ang = (float)t * invf;
            float rev = ang * 0.15915494309189535f;
            float fr = (rev - rintf(rev)) * 6.283185307179586f;  // [-pi, pi]
            float sv = __sinf(fr), cv = __cosf(fr);
            float x1 = acc[i][jp][ii], x2 = acc[i][jp + 2][ii];
            store_out(&C[(long)(r0 + ii) * N + cn],      (x1 * cv - x2 * sv) * sc);
            store_out(&C[(long)(r0 + ii) * N + cn + 32], (x1 * sv + x2 * cv) * sc);
          }
        }
      }
    }
  } else {
#pragma unroll
    for (int i = 0; i < 4; ++i)
#pragma unroll
      for (int j = 0; j < 4; ++j) {
        int r = m0 + mw + i * 16 + g * 4;
        int cn = n0 + nw + j * 16 + l15;
#pragma unroll
        for (int ii = 0; ii < 4; ++ii)
          store_out(&C[(long)(r + ii) * N + cn], acc[i][j][ii]);
      }
  }
}

// ---------------- Flash attention: 64-key tiles, dbuf, XCD-local K/V, CU-balanced ----------------
// Block remap (see file header): each XCD owns 2 (b,kvh) pairs -> K/V panels
// L2-resident; same-CU blocks alternate qt/15-qt -> 68 tiles/CU.
// LDS: Ks 2x8K + Vs 2x8K = 32768 B. P stays in registers (permlane relayout).
__global__ __launch_bounds__(256, 4)
void flash_attn(const bf16_t* __restrict__ qkv, const bf16_t* __restrict__ vt,
                bf16_t* __restrict__ y) {
  constexpr int T = 2048, LDQ = 3072;
  __shared__ __align__(16) bf16_t Ks[2][64 * 64];   // [kk][d], chunk-swizzled
  __shared__ __align__(16) bf16_t Vs[2][64 * 64];   // [d][kk], chunk-swizzled
  const int tid = threadIdx.x, wave = tid >> 6, lane = tid & 63, g = lane >> 4, l15 = lane & 15;
  // ---- XCD-aware decode ----
  const int L = blockIdx.x + (blockIdx.y << 4) + (blockIdx.z << 9);
  const int c = L & 7, s = L >> 3;
  const int t8 = s & 31, u = s >> 5;
  const int p = c * 2 + (t8 & 1);      // b*8 + kvh
  const int b = p >> 3, kvh = p & 7;
  const int h = kvh * 4 + u;           // q-head within the kv group
  const int j0 = t8 >> 1;
  const int qt0 = (j0 < 8) ? (15 - j0) : (j0 - 8);
  const int qt = (u & 1) ? (15 - qt0) : qt0;   // per-CU balance
  const bf16_t* qbase = qkv + (long)(b * T + qt * 128) * LDQ + h * 64;
  const bf16_t* kbase = qkv + (long)(b * T) * LDQ + 2048 + kvh * 64;
  const bf16_t* vbase = vt + (long)((b * 8 + kvh) * 64) * T;

  // Q fragments (B-operand layout: n=q=l15, kdim=g*8+jj)
  bf16x8 qf[2][2];
#pragma unroll
  for (int ms = 0; ms < 2; ++ms)
#pragma unroll
    for (int hh = 0; hh < 2; ++hh)
      qf[ms][hh] = *(const bf16x8*)(qbase + (long)(wave * 32 + ms * 16 + l15) * LDQ + hh * 32 + g * 8);

  bf16x8 onef;
#pragma unroll
  for (int i = 0; i < 8; ++i) onef[i] = (__bf16)1.0f;

  f32x4 o[2][4] = {};
  f32x4 lacc[2] = {};
  const f32x4 fz = {0.f, 0.f, 0.f, 0.f};

  // hoisted staging addresses: c = i*256+tid, i in {0,1}
  const int c0 = tid, c1 = 256 + tid;
  const int row0 = c0 >> 3, pos0 = c0 & 7, sw0 = ((pos0 ^ (row0 & 7)) * 8);
  const int row1 = c1 >> 3, pos1 = c1 & 7, sw1 = ((pos1 ^ (row1 & 7)) * 8);
  const bf16_t* kp0 = kbase + (long)row0 * LDQ + sw0;
  const bf16_t* kp1 = kbase + (long)row1 * LDQ + sw1;
  const bf16_t* vp0 = vbase + (long)row0 * T + sw0;
  const bf16_t* vp1 = vbase + (long)row1 * T + sw1;
  const int l0 = c0 * 8, l1 = c1 * 8;

  auto stage = [&](int buf) {
    gload_lds16(kp0, &Ks[buf][l0]);
    gload_lds16(vp0, &Vs[buf][l0]);
    gload_lds16(kp1, &Ks[buf][l1]);
    gload_lds16(vp1, &Vs[buf][l1]);
    kp0 += 64 * LDQ; kp1 += 64 * LDQ;
    vp0 += 64;       vp1 += 64;
  };

  stage(0);
  const int nkt = 2 * qt + 2;
  for (int kt = 0; kt < nkt; ++kt) {
    __syncthreads();               // vmcnt(0) drain precedes barrier: buf[kt&1] ready
    if (kt + 1 < nkt) stage((kt + 1) & 1);
    const bf16_t* Kc = Ks[kt & 1];
    const bf16_t* Vc = Vs[kt & 1];
    const int dk = kt - 2 * qt;        // >=0 only on the two diagonal tiles
    const bool diag = (dk >= 0);

#pragma unroll
    for (int ks = 0; ks < 2; ++ks) {
      // ---- S^T chunk: rows k = ks*32 + nsl*16 + g*4+ii, cols q = l15 ----
      f32x4 s2[2][2];
      __builtin_amdgcn_s_setprio(1);
#pragma unroll
      for (int nsl = 0; nsl < 2; ++nsl) {
        int krow = ks * 32 + nsl * 16 + l15;
        bf16x8 kf0 = *(const bf16x8*)&Kc[krow * 64 + ((g ^ (l15 & 7)) * 8)];
        bf16x8 kf1 = *(const bf16x8*)&Kc[krow * 64 + (((4 + g) ^ (l15 & 7)) * 8)];
#pragma unroll
        for (int ms = 0; ms < 2; ++ms) {
          f32x4 tt = __builtin_amdgcn_mfma_f32_16x16x32_bf16(kf0, qf[ms][0], fz, 0, 0, 0);
          s2[ms][nsl] = __builtin_amdgcn_mfma_f32_16x16x32_bf16(kf1, qf[ms][1], tt, 0, 0, 0);
        }
      }
      __builtin_amdgcn_s_setprio(0);
      // ---- P = exp2(S) (q pre-scaled), mask, pack, permlane relayout (no LDS) ----
      // S^T regs: lane(g,l15) nsl,ii -> P[q=l15(+ms*16)][k = nsl*16+g*4+ii]
      // A-frag:   lane(g,l15) jj     -> P[q=l15(+ms*16)][k = g*8+jj]
      bf16x8 pf[2];
#pragma unroll
      for (int ms = 0; ms < 2; ++ms) {
        unsigned dw[4];
#pragma unroll
        for (int nsl = 0; nsl < 2; ++nsl) {
          unsigned u4[4];
#pragma unroll
          for (int ii = 0; ii < 4; ++ii) {
            float pp = fast_exp2(s2[ms][nsl][ii]);
            if (diag && (dk * 64 + ks * 32 + nsl * 16 + g * 4 + ii >
                         wave * 32 + ms * 16 + l15)) pp = 0.f;
            u4[ii] = __builtin_bit_cast(unsigned int, pp);
          }
          dw[nsl * 2 + 0] = pack_bf16_rnd(u4[0], u4[1]);   // k = nsl*16+g*4 + {0,1}
          dw[nsl * 2 + 1] = pack_bf16_rnd(u4[2], u4[3]);   // k = nsl*16+g*4 + {2,3}
        }
        // rows(g) of dw[0],dw[2]: [S0g0..] / [S2g0..]; after 32swap+16swap:
        // dw[0] = [S0g0 S0g2 S2g0 S2g2] = w0, dw[2] = [S0g1 S0g3 S2g1 S2g3] = w2
        permlane32_swap(dw[0], dw[2]);
        permlane16_swap(dw[0], dw[2]);
        permlane32_swap(dw[1], dw[3]);
        permlane16_swap(dw[1], dw[3]);
        uint4 uu = {dw[0], dw[1], dw[2], dw[3]};
        pf[ms] = __builtin_bit_cast(bf16x8, uu);
        lacc[ms] = __builtin_amdgcn_mfma_f32_16x16x32_bf16(pf[ms], onef, lacc[ms], 0, 0, 0);
      }
      // ---- PV chunk ----
      __builtin_amdgcn_s_setprio(1);
#pragma unroll
      for (int ds = 0; ds < 4; ++ds) {
        bf16x8 vf = *(const bf16x8*)&Vc[(ds * 16 + l15) * 64 + (((ks * 4 + g) ^ (l15 & 7)) * 8)];
        o[0][ds] = __builtin_amdgcn_mfma_f32_16x16x32_bf16(pf[0], vf, o[0][ds], 0, 0, 0);
        o[1][ds] = __builtin_amdgcn_mfma_f32_16x16x32_bf16(pf[1], vf, o[1][ds], 0, 0, 0);
      }
      __builtin_amdgcn_s_setprio(0);
    }
  }

  // ---- epilogue: normalize, transpose 16x64 halves via LDS (reuse Vs), b128 stores ----
  __syncthreads();                         // all waves done reading Ks/Vs
  bf16_t* E = (bf16_t*)&Vs[0][0] + wave * 1152;  // 16*72 = 1152 per wave
#pragma unroll
  for (int ms = 0; ms < 2; ++ms) {
    f32x4 linv;
#pragma unroll
    for (int ii = 0; ii < 4; ++ii) linv[ii] = 1.0f / lacc[ms][ii];
#pragma unroll
    for (int ds = 0; ds < 4; ++ds)
#pragma unroll
      for (int ii = 0; ii < 4; ++ii)
        E[(g * 4 + ii) * 72 + ds * 16 + l15] = __float2bfloat16(o[ms][ds][ii] * linv[ii]);
    // wave-private region, in-order DS ops -> no barrier
    bf16x8 r0 = *(const bf16x8*)&E[l15 * 72 + g * 16];
    bf16x8 r1 = *(const bf16x8*)&E[l15 * 72 + g * 16 + 8];
    int q = qt * 128 + wave * 32 + ms * 16 + l15;
    *(bf16x8*)&y[(long)(b * T + q) * 2048 + h * 64 + g * 16] = r0;
    *(bf16x8*)&y[(long)(b * T + q) * 2048 + h * 64 + g * 16 + 8] = r1;
  }
}

extern "C" void kernel_launch(void* const* d_in, const int* in_sizes, int n_in,
                              void* d_out, int out_size, void* d_ws, size_t ws_size,
                              hipStream_t stream) {
  const float* x  = (const float*)d_in[0];
  const float* Wq = (const float*)d_in[1];
  const float* Wk = (const float*)d_in[2];
  const float* Wv = (const float*)d_in[3];
  const float* Wo = (const float*)d_in[4];
  float* out = (float*)d_out;
  char* ws = (char*)d_ws;

  bf16_t* xb    = (bf16_t*)(ws);                                     // 16.78 MB (reused as y)
  bf16_t* wqkvt = (bf16_t*)(ws + 16777216);                          // 12.58 MB
  bf16_t* wot   = (bf16_t*)(ws + 16777216 + 12582912);               // 8.39 MB
  bf16_t* qkvb  = (bf16_t*)(ws + 16777216 + 12582912 + 8388608);     // 25.17 MB
  bf16_t* vtb   = (bf16_t*)(ws + 16777216 + 12582912 + 8388608 + 25165824); // 4.19 MB
  bf16_t* yb = xb;  // x dead after QKV GEMM

  prep<<<12288, 256, 0, stream>>>(x, Wq, Wk, Wv, Wo, xb, wqkvt, wot);
  gemm_bt<bf16_t, 1><<<dim3(24, 32), 256, 0, stream>>>(xb, wqkvt, qkvb, 4096, 3072, 2048, vtb);
  flash_attn<<<dim3(16, 32, 2), 256, 0, stream>>>(qkvb, vtb, yb);
  gemm_bt<float, 0><<<dim3(16, 32), 256, 0, stream>>>(yb, wot, out, 4096, 2048, 2048, nullptr);
}

// Round 9
// 268.015 us; speedup vs baseline: 1.1761x; 1.0114x over previous
//
#include <hip/hip_runtime.h>
#include <hip/hip_bf16.h>

// GQA: B=2, T=2048, C=2048, H=32, KV=8, D=64, n_rep=4, causal, RoPE base 1e4.
// Round 15 (base = round-14 green, 271.1us; flash 67.1 w/ XCD-local K/V):
// GEMM-only change: XCD-chunked block remap (T1) for both gemm_bt launches.
// Old: XCD = L%8 -> A/B panels sprayed across all XCDs (working set >> 4MB L2).
// New: XCD c owns a contiguous stripe of gridDim.y/8 = 4 m-rows (4 A-panels =
// 2MB, L2-resident, reused by gridDim.x blocks each); B streams via L3.
//   L = bx + gx*by; c = L&7; rr = L>>3; bx' = rr % gx; by' = c*(gy>>3) + rr/gx.
// Bijective (gy=32 divisible by 8 for both gemms). K-loop, staging, epilogue,
// flash, prep: byte-identical to round-14 green.

typedef __hip_bfloat16 bf16_t;
typedef __bf16 bf16x8 __attribute__((ext_vector_type(8)));
typedef float f32x4 __attribute__((ext_vector_type(4)));

#define AS1 __attribute__((address_space(1)))
#define AS3 __attribute__((address_space(3)))

__device__ __forceinline__ void gload_lds16(const void* g, void* l) {
  __builtin_amdgcn_global_load_lds((const AS1 unsigned int*)g,
                                   (AS3 unsigned int*)l, 16, 0, 0);
}

__device__ __forceinline__ float fast_exp2(float x) {
#if __has_builtin(__builtin_amdgcn_exp2f)
  return __builtin_amdgcn_exp2f(x);
#else
  return exp2f(x);
#endif
}

__device__ __forceinline__ unsigned int pack_bf16_rnd(unsigned int u0, unsigned int u1) {
  u0 += 0x8000u; u1 += 0x8000u;
#if __has_builtin(__builtin_amdgcn_perm)
  return __builtin_amdgcn_perm(u1, u0, 0x07060302u);
#else
  return (u1 & 0xffff0000u) | (u0 >> 16);
#endif
}

// v_permlane32_swap_b32 a,b : a' = [a.lo | b.lo], b' = [a.hi | b.hi]  (32-lane halves)
// v_permlane16_swap_b32 a,b : a' = [a0 b0 a2 b2], b' = [a1 b1 a3 b3]  (16-lane rows)
__device__ __forceinline__ void permlane32_swap(unsigned& a, unsigned& b) {
  asm volatile("v_permlane32_swap_b32 %0, %1" : "+v"(a), "+v"(b));
}
__device__ __forceinline__ void permlane16_swap(unsigned& a, unsigned& b) {
  asm volatile("v_permlane16_swap_b32 %0, %1" : "+v"(a), "+v"(b));
}

__device__ __forceinline__ void store_out(float* p, float v) { *p = v; }
__device__ __forceinline__ void store_out(bf16_t* p, float v) { *p = __float2bfloat16(v); }

// ---------------- prep: cast x + transpose/cast all 4 weights, one launch ----------------
__global__ void prep(const float* __restrict__ x, const float* __restrict__ Wq,
                     const float* __restrict__ Wk, const float* __restrict__ Wv,
                     const float* __restrict__ Wo, bf16_t* __restrict__ xb,
                     bf16_t* __restrict__ wqkvt, bf16_t* __restrict__ wot) {
  const int bid = blockIdx.x, tid = threadIdx.x;
  if (bid < 2048) {
#pragma unroll
    for (int k = 0; k < 4; ++k) {
      int i = bid * 1024 + k * 256 + tid;
      float4 v = ((const float4*)x)[i];
      bf16_t o[4] = {__float2bfloat16(v.x), __float2bfloat16(v.y),
                     __float2bfloat16(v.z), __float2bfloat16(v.w)};
      ((ushort4*)xb)[i] = *(ushort4*)o;
    }
    return;
  }
  const float* W; bf16_t* dst; int ncols, bx, by;
  if (bid < 6144)       { int l = bid - 2048;  W = Wq; dst = wqkvt;               ncols = 2048; bx = l & 63; by = l >> 6; }
  else if (bid < 10240) { int l = bid - 6144;  W = Wo; dst = wot;                 ncols = 2048; bx = l & 63; by = l >> 6; }
  else if (bid < 11264) { int l = bid - 10240; W = Wk; dst = wqkvt + 2048L * 2048; ncols = 512; bx = l & 15; by = l >> 4; }
  else                  { int l = bid - 11264; W = Wv; dst = wqkvt + 2560L * 2048; ncols = 512; bx = l & 15; by = l >> 4; }
  __shared__ float tile[32][33];
  const int tx = tid & 31, ty = tid >> 5;
  const int n0 = bx * 32, k0 = by * 32;
#pragma unroll
  for (int i = 0; i < 4; ++i)
    tile[ty + 8 * i][tx] = W[(long)(k0 + ty + 8 * i) * ncols + n0 + tx];
  __syncthreads();
#pragma unroll
  for (int i = 0; i < 4; ++i)
    dst[(long)(n0 + ty + 8 * i) * 2048 + k0 + tx] = __float2bfloat16(tile[tx][ty + 8 * i]);
}

// ---------------- GEMM: C[M][N] = A[M][K] * Bt[N][K]^T, bf16 in, fp32 acc ----------------
// MODE 0: plain store. MODE 1 (QKV): fused epilogue —
//   q cols (<2048):   RoPE on fp32 acc, pre-scale 0.125*log2(e), bf16 store
//   k cols (<2560):   RoPE on fp32 acc, bf16 store
//   v cols (>=2560):  no rope; store transposed into vt[(b*8+kv)*64+d][T]
template <typename OutT, int MODE>
__global__ __launch_bounds__(256, 3)
void gemm_bt(const bf16_t* __restrict__ A, const bf16_t* __restrict__ Bt,
             OutT* __restrict__ C, int M, int N, int K, bf16_t* __restrict__ vt) {
  __shared__ __align__(16) bf16_t As[128 * 64];
  __shared__ __align__(16) bf16_t Bs[128 * 64];
  const int tid = threadIdx.x;
  const int wave = tid >> 6, lane = tid & 63, g = lane >> 4, l15 = lane & 15;
  // ---- XCD-chunked remap (T1): XCD = L&7 owns a contiguous by-stripe ----
  // (requires gridDim.y % 8 == 0: 32 for both launches)
  const int Lg = blockIdx.x + gridDim.x * blockIdx.y;
  const int cx = Lg & 7, rr = Lg >> 3;
  const int bxr = rr % gridDim.x;
  const int byr = cx * (gridDim.y >> 3) + rr / gridDim.x;
  const int m0 = byr * 128, n0 = bxr * 128;
  const int mw = (wave >> 1) * 64, nw = (wave & 1) * 64;
  const bf16_t* Ab = A + (long)m0 * K;
  const bf16_t* Bb = Bt + (long)n0 * K;
  f32x4 acc[4][4] = {};
  const int nkt = K >> 6;
  for (int kt = 0; kt < nkt; ++kt) {
    __syncthreads();
#pragma unroll
    for (int i = 0; i < 4; ++i) {
      int c = i * 256 + tid;
      int row = c >> 3, pos = c & 7;
      int gcol = ((pos ^ (row & 7)) * 8);
      gload_lds16(Ab + (long)row * K + kt * 64 + gcol, &As[c * 8]);
      gload_lds16(Bb + (long)row * K + kt * 64 + gcol, &Bs[c * 8]);
    }
    __syncthreads();
#pragma unroll
    for (int ks = 0; ks < 2; ++ks) {
      bf16x8 af[4], bq[4];
#pragma unroll
      for (int i = 0; i < 4; ++i) {
        int pos = ((ks * 4 + g) ^ (l15 & 7)) * 8;
        af[i] = *(const bf16x8*)&As[(mw + i * 16 + l15) * 64 + pos];
        bq[i] = *(const bf16x8*)&Bs[(nw + i * 16 + l15) * 64 + pos];
      }
#pragma unroll
      for (int i = 0; i < 4; ++i)
#pragma unroll
        for (int j = 0; j < 4; ++j)
          acc[i][j] = __builtin_amdgcn_mfma_f32_16x16x32_bf16(af[i], bq[j], acc[i][j], 0, 0, 0);
    }
  }

  if (MODE == 1) {
    const int cnb = n0 + nw;                 // wave's head base col (mult of 64)
    if (cnb >= 2560) {
      // ---- V: store transposed into vt[((b*8+kv)*64 + d)*2048 + t] ----
      const int kv = (cnb - 2560) >> 6;
      const int bb = m0 >> 11;
#pragma unroll
      for (int i = 0; i < 4; ++i) {
        const int t0 = (m0 & 2047) + mw + i * 16 + g * 4;
#pragma unroll
        for (int j = 0; j < 4; ++j) {
          const int d = j * 16 + l15;
          bf16_t o4[4];
#pragma unroll
          for (int ii = 0; ii < 4; ++ii) o4[ii] = __float2bfloat16(acc[i][j][ii]);
          *(ushort4*)&vt[((long)((bb * 8 + kv) * 64 + d)) * 2048 + t0] = *(ushort4*)o4;
        }
      }
    } else {
      // ---- Q/K: RoPE in-register (pair (d, d+32) = acc[i][jp] / acc[i][jp+2]) ----
      const float sc = (cnb < 2048) ? 0.18033688011112043f : 1.0f;  // 0.125*log2(e) for q
#pragma unroll
      for (int jp = 0; jp < 2; ++jp) {
        const int d = jp * 16 + l15;
        const float invf = exp2f(-(float)d * 0.4152410118074032f);  // log2(10000)/32
        const int cn = cnb + jp * 16 + l15;
#pragma unroll
        for (int i = 0; i < 4; ++i) {
          const int r0 = m0 + mw + i * 16 + g * 4;
#pragma unroll
          for (int ii = 0; ii < 4; ++ii) {
            const int t = (r0 + ii) & 2047;
            float ang = (float)t * invf;
            float rev = ang * 0.15915494309189535f;
            float fr = (rev - rintf(rev)) * 6.283185307179586f;  // [-pi, pi]
            float sv = __sinf(fr), cv = __cosf(fr);
            float x1 = acc[i][jp][ii], x2 = acc[i][jp + 2][ii];
            store_out(&C[(long)(r0 + ii) * N + cn],      (x1 * cv - x2 * sv) * sc);
            store_out(&C[(long)(r0 + ii) * N + cn + 32], (x1 * sv + x2 * cv) * sc);
          }
        }
      }
    }
  } else {
#pragma unroll
    for (int i = 0; i < 4; ++i)
#pragma unroll
      for (int j = 0; j < 4; ++j) {
        int r = m0 + mw + i * 16 + g * 4;
        int cn = n0 + nw + j * 16 + l15;
#pragma unroll
        for (int ii = 0; ii < 4; ++ii)
          store_out(&C[(long)(r + ii) * N + cn], acc[i][j][ii]);
      }
  }
}

// ---------------- Flash attention: 64-key tiles, dbuf, XCD-local K/V, CU-balanced ----------------
// Block remap: each XCD owns 2 (b,kvh) pairs -> K/V panels L2-resident;
// same-CU blocks alternate qt/15-qt -> 68 tiles/CU.
// LDS: Ks 2x8K + Vs 2x8K = 32768 B. P stays in registers (permlane relayout).
__global__ __launch_bounds__(256, 4)
void flash_attn(const bf16_t* __restrict__ qkv, const bf16_t* __restrict__ vt,
                bf16_t* __restrict__ y) {
  constexpr int T = 2048, LDQ = 3072;
  __shared__ __align__(16) bf16_t Ks[2][64 * 64];   // [kk][d], chunk-swizzled
  __shared__ __align__(16) bf16_t Vs[2][64 * 64];   // [d][kk], chunk-swizzled
  const int tid = threadIdx.x, wave = tid >> 6, lane = tid & 63, g = lane >> 4, l15 = lane & 15;
  // ---- XCD-aware decode ----
  const int L = blockIdx.x + (blockIdx.y << 4) + (blockIdx.z << 9);
  const int c = L & 7, s = L >> 3;
  const int t8 = s & 31, u = s >> 5;
  const int p = c * 2 + (t8 & 1);      // b*8 + kvh
  const int b = p >> 3, kvh = p & 7;
  const int h = kvh * 4 + u;           // q-head within the kv group
  const int j0 = t8 >> 1;
  const int qt0 = (j0 < 8) ? (15 - j0) : (j0 - 8);
  const int qt = (u & 1) ? (15 - qt0) : qt0;   // per-CU balance
  const bf16_t* qbase = qkv + (long)(b * T + qt * 128) * LDQ + h * 64;
  const bf16_t* kbase = qkv + (long)(b * T) * LDQ + 2048 + kvh * 64;
  const bf16_t* vbase = vt + (long)((b * 8 + kvh) * 64) * T;

  // Q fragments (B-operand layout: n=q=l15, kdim=g*8+jj)
  bf16x8 qf[2][2];
#pragma unroll
  for (int ms = 0; ms < 2; ++ms)
#pragma unroll
    for (int hh = 0; hh < 2; ++hh)
      qf[ms][hh] = *(const bf16x8*)(qbase + (long)(wave * 32 + ms * 16 + l15) * LDQ + hh * 32 + g * 8);

  bf16x8 onef;
#pragma unroll
  for (int i = 0; i < 8; ++i) onef[i] = (__bf16)1.0f;

  f32x4 o[2][4] = {};
  f32x4 lacc[2] = {};
  const f32x4 fz = {0.f, 0.f, 0.f, 0.f};

  // hoisted staging addresses: c = i*256+tid, i in {0,1}
  const int c0 = tid, c1 = 256 + tid;
  const int row0 = c0 >> 3, pos0 = c0 & 7, sw0 = ((pos0 ^ (row0 & 7)) * 8);
  const int row1 = c1 >> 3, pos1 = c1 & 7, sw1 = ((pos1 ^ (row1 & 7)) * 8);
  const bf16_t* kp0 = kbase + (long)row0 * LDQ + sw0;
  const bf16_t* kp1 = kbase + (long)row1 * LDQ + sw1;
  const bf16_t* vp0 = vbase + (long)row0 * T + sw0;
  const bf16_t* vp1 = vbase + (long)row1 * T + sw1;
  const int l0 = c0 * 8, l1 = c1 * 8;

  auto stage = [&](int buf) {
    gload_lds16(kp0, &Ks[buf][l0]);
    gload_lds16(vp0, &Vs[buf][l0]);
    gload_lds16(kp1, &Ks[buf][l1]);
    gload_lds16(vp1, &Vs[buf][l1]);
    kp0 += 64 * LDQ; kp1 += 64 * LDQ;
    vp0 += 64;       vp1 += 64;
  };

  stage(0);
  const int nkt = 2 * qt + 2;
  for (int kt = 0; kt < nkt; ++kt) {
    __syncthreads();               // vmcnt(0) drain precedes barrier: buf[kt&1] ready
    if (kt + 1 < nkt) stage((kt + 1) & 1);
    const bf16_t* Kc = Ks[kt & 1];
    const bf16_t* Vc = Vs[kt & 1];
    const int dk = kt - 2 * qt;        // >=0 only on the two diagonal tiles
    const bool diag = (dk >= 0);

#pragma unroll
    for (int ks = 0; ks < 2; ++ks) {
      // ---- S^T chunk: rows k = ks*32 + nsl*16 + g*4+ii, cols q = l15 ----
      f32x4 s2[2][2];
      __builtin_amdgcn_s_setprio(1);
#pragma unroll
      for (int nsl = 0; nsl < 2; ++nsl) {
        int krow = ks * 32 + nsl * 16 + l15;
        bf16x8 kf0 = *(const bf16x8*)&Kc[krow * 64 + ((g ^ (l15 & 7)) * 8)];
        bf16x8 kf1 = *(const bf16x8*)&Kc[krow * 64 + (((4 + g) ^ (l15 & 7)) * 8)];
#pragma unroll
        for (int ms = 0; ms < 2; ++ms) {
          f32x4 tt = __builtin_amdgcn_mfma_f32_16x16x32_bf16(kf0, qf[ms][0], fz, 0, 0, 0);
          s2[ms][nsl] = __builtin_amdgcn_mfma_f32_16x16x32_bf16(kf1, qf[ms][1], tt, 0, 0, 0);
        }
      }
      __builtin_amdgcn_s_setprio(0);
      // ---- P = exp2(S) (q pre-scaled), mask, pack, permlane relayout (no LDS) ----
      // S^T regs: lane(g,l15) nsl,ii -> P[q=l15(+ms*16)][k = nsl*16+g*4+ii]
      // A-frag:   lane(g,l15) jj     -> P[q=l15(+ms*16)][k = g*8+jj]
      bf16x8 pf[2];
#pragma unroll
      for (int ms = 0; ms < 2; ++ms) {
        unsigned dw[4];
#pragma unroll
        for (int nsl = 0; nsl < 2; ++nsl) {
          unsigned u4[4];
#pragma unroll
          for (int ii = 0; ii < 4; ++ii) {
            float pp = fast_exp2(s2[ms][nsl][ii]);
            if (diag && (dk * 64 + ks * 32 + nsl * 16 + g * 4 + ii >
                         wave * 32 + ms * 16 + l15)) pp = 0.f;
            u4[ii] = __builtin_bit_cast(unsigned int, pp);
          }
          dw[nsl * 2 + 0] = pack_bf16_rnd(u4[0], u4[1]);   // k = nsl*16+g*4 + {0,1}
          dw[nsl * 2 + 1] = pack_bf16_rnd(u4[2], u4[3]);   // k = nsl*16+g*4 + {2,3}
        }
        // rows(g) of dw[0],dw[2]: [S0g0..] / [S2g0..]; after 32swap+16swap:
        // dw[0] = [S0g0 S0g2 S2g0 S2g2] = w0, dw[2] = [S0g1 S0g3 S2g1 S2g3] = w2
        permlane32_swap(dw[0], dw[2]);
        permlane16_swap(dw[0], dw[2]);
        permlane32_swap(dw[1], dw[3]);
        permlane16_swap(dw[1], dw[3]);
        uint4 uu = {dw[0], dw[1], dw[2], dw[3]};
        pf[ms] = __builtin_bit_cast(bf16x8, uu);
        lacc[ms] = __builtin_amdgcn_mfma_f32_16x16x32_bf16(pf[ms], onef, lacc[ms], 0, 0, 0);
      }
      // ---- PV chunk ----
      __builtin_amdgcn_s_setprio(1);
#pragma unroll
      for (int ds = 0; ds < 4; ++ds) {
        bf16x8 vf = *(const bf16x8*)&Vc[(ds * 16 + l15) * 64 + (((ks * 4 + g) ^ (l15 & 7)) * 8)];
        o[0][ds] = __builtin_amdgcn_mfma_f32_16x16x32_bf16(pf[0], vf, o[0][ds], 0, 0, 0);
        o[1][ds] = __builtin_amdgcn_mfma_f32_16x16x32_bf16(pf[1], vf, o[1][ds], 0, 0, 0);
      }
      __builtin_amdgcn_s_setprio(0);
    }
  }

  // ---- epilogue: normalize, transpose 16x64 halves via LDS (reuse Vs), b128 stores ----
  __syncthreads();                         // all waves done reading Ks/Vs
  bf16_t* E = (bf16_t*)&Vs[0][0] + wave * 1152;  // 16*72 = 1152 per wave
#pragma unroll
  for (int ms = 0; ms < 2; ++ms) {
    f32x4 linv;
#pragma unroll
    for (int ii = 0; ii < 4; ++ii) linv[ii] = 1.0f / lacc[ms][ii];
#pragma unroll
    for (int ds = 0; ds < 4; ++ds)
#pragma unroll
      for (int ii = 0; ii < 4; ++ii)
        E[(g * 4 + ii) * 72 + ds * 16 + l15] = __float2bfloat16(o[ms][ds][ii] * linv[ii]);
    // wave-private region, in-order DS ops -> no barrier
    bf16x8 r0 = *(const bf16x8*)&E[l15 * 72 + g * 16];
    bf16x8 r1 = *(const bf16x8*)&E[l15 * 72 + g * 16 + 8];
    int q = qt * 128 + wave * 32 + ms * 16 + l15;
    *(bf16x8*)&y[(long)(b * T + q) * 2048 + h * 64 + g * 16] = r0;
    *(bf16x8*)&y[(long)(b * T + q) * 2048 + h * 64 + g * 16 + 8] = r1;
  }
}

extern "C" void kernel_launch(void* const* d_in, const int* in_sizes, int n_in,
                              void* d_out, int out_size, void* d_ws, size_t ws_size,
                              hipStream_t stream) {
  const float* x  = (const float*)d_in[0];
  const float* Wq = (const float*)d_in[1];
  const float* Wk = (const float*)d_in[2];
  const float* Wv = (const float*)d_in[3];
  const float* Wo = (const float*)d_in[4];
  float* out = (float*)d_out;
  char* ws = (char*)d_ws;

  bf16_t* xb    = (bf16_t*)(ws);                                     // 16.78 MB (reused as y)
  bf16_t* wqkvt = (bf16_t*)(ws + 16777216);                          // 12.58 MB
  bf16_t* wot   = (bf16_t*)(ws + 16777216 + 12582912);               // 8.39 MB
  bf16_t* qkvb  = (bf16_t*)(ws + 16777216 + 12582912 + 8388608);     // 25.17 MB
  bf16_t* vtb   = (bf16_t*)(ws + 16777216 + 12582912 + 8388608 + 25165824); // 4.19 MB
  bf16_t* yb = xb;  // x dead after QKV GEMM

  prep<<<12288, 256, 0, stream>>>(x, Wq, Wk, Wv, Wo, xb, wqkvt, wot);
  gemm_bt<bf16_t, 1><<<dim3(24, 32), 256, 0, stream>>>(xb, wqkvt, qkvb, 4096, 3072, 2048, vtb);
  flash_attn<<<dim3(16, 32, 2), 256, 0, stream>>>(qkvb, vtb, yb);
  gemm_bt<float, 0><<<dim3(16, 32), 256, 0, stream>>>(yb, wot, out, 4096, 2048, 2048, nullptr);
}

// Round 10
// 257.800 us; speedup vs baseline: 1.2227x; 1.0396x over previous
//
#include <hip/hip_runtime.h>
#include <hip/hip_bf16.h>

// GQA: B=2, T=2048, C=2048, H=32, KV=8, D=64, n_rep=4, causal, RoPE base 1e4.
// Round 16 (base = round-15 green, 268.0us; flash 67.7): SINGLE change —
// P pack via v_cvt_pk_bf16_f32 (1 VALU op/dword, RNE; T12 recipe form) instead
// of pack_bf16_rnd (3 ops/dword). -32 VALU ops/tile in the dominant VALU pipe.
// Forensics: cvt_pk was bundled in round-3's fail, but round-4 failed WITH
// pack_bf16_rnd restored -> loop-split convicted, cvt_pk never was. This is
// the clean single-variable trial. Everything else byte-identical to round-15:
// XCD-local flash K/V remap, XCD-chunked gemm remap, fused RoPE/VT epilogue,
// permlane P-relayout, setprio, single kt loop with runtime diag mask.

typedef __hip_bfloat16 bf16_t;
typedef __bf16 bf16x8 __attribute__((ext_vector_type(8)));
typedef float f32x4 __attribute__((ext_vector_type(4)));

#define AS1 __attribute__((address_space(1)))
#define AS3 __attribute__((address_space(3)))

__device__ __forceinline__ void gload_lds16(const void* g, void* l) {
  __builtin_amdgcn_global_load_lds((const AS1 unsigned int*)g,
                                   (AS3 unsigned int*)l, 16, 0, 0);
}

__device__ __forceinline__ float fast_exp2(float x) {
#if __has_builtin(__builtin_amdgcn_exp2f)
  return __builtin_amdgcn_exp2f(x);
#else
  return exp2f(x);
#endif
}

// dst.lo16 = bf16_rne(a), dst.hi16 = bf16_rne(b)  (T12 recipe form, gfx950)
__device__ __forceinline__ unsigned cvt_pk_bf16(float a, float b) {
  unsigned r;
  asm("v_cvt_pk_bf16_f32 %0, %1, %2" : "=v"(r) : "v"(a), "v"(b));
  return r;
}

// v_permlane32_swap_b32 a,b : a' = [a.lo | b.lo], b' = [a.hi | b.hi]  (32-lane halves)
// v_permlane16_swap_b32 a,b : a' = [a0 b0 a2 b2], b' = [a1 b1 a3 b3]  (16-lane rows)
__device__ __forceinline__ void permlane32_swap(unsigned& a, unsigned& b) {
  asm volatile("v_permlane32_swap_b32 %0, %1" : "+v"(a), "+v"(b));
}
__device__ __forceinline__ void permlane16_swap(unsigned& a, unsigned& b) {
  asm volatile("v_permlane16_swap_b32 %0, %1" : "+v"(a), "+v"(b));
}

__device__ __forceinline__ void store_out(float* p, float v) { *p = v; }
__device__ __forceinline__ void store_out(bf16_t* p, float v) { *p = __float2bfloat16(v); }

// ---------------- prep: cast x + transpose/cast all 4 weights, one launch ----------------
__global__ void prep(const float* __restrict__ x, const float* __restrict__ Wq,
                     const float* __restrict__ Wk, const float* __restrict__ Wv,
                     const float* __restrict__ Wo, bf16_t* __restrict__ xb,
                     bf16_t* __restrict__ wqkvt, bf16_t* __restrict__ wot) {
  const int bid = blockIdx.x, tid = threadIdx.x;
  if (bid < 2048) {
#pragma unroll
    for (int k = 0; k < 4; ++k) {
      int i = bid * 1024 + k * 256 + tid;
      float4 v = ((const float4*)x)[i];
      bf16_t o[4] = {__float2bfloat16(v.x), __float2bfloat16(v.y),
                     __float2bfloat16(v.z), __float2bfloat16(v.w)};
      ((ushort4*)xb)[i] = *(ushort4*)o;
    }
    return;
  }
  const float* W; bf16_t* dst; int ncols, bx, by;
  if (bid < 6144)       { int l = bid - 2048;  W = Wq; dst = wqkvt;               ncols = 2048; bx = l & 63; by = l >> 6; }
  else if (bid < 10240) { int l = bid - 6144;  W = Wo; dst = wot;                 ncols = 2048; bx = l & 63; by = l >> 6; }
  else if (bid < 11264) { int l = bid - 10240; W = Wk; dst = wqkvt + 2048L * 2048; ncols = 512; bx = l & 15; by = l >> 4; }
  else                  { int l = bid - 11264; W = Wv; dst = wqkvt + 2560L * 2048; ncols = 512; bx = l & 15; by = l >> 4; }
  __shared__ float tile[32][33];
  const int tx = tid & 31, ty = tid >> 5;
  const int n0 = bx * 32, k0 = by * 32;
#pragma unroll
  for (int i = 0; i < 4; ++i)
    tile[ty + 8 * i][tx] = W[(long)(k0 + ty + 8 * i) * ncols + n0 + tx];
  __syncthreads();
#pragma unroll
  for (int i = 0; i < 4; ++i)
    dst[(long)(n0 + ty + 8 * i) * 2048 + k0 + tx] = __float2bfloat16(tile[tx][ty + 8 * i]);
}

// ---------------- GEMM: C[M][N] = A[M][K] * Bt[N][K]^T, bf16 in, fp32 acc ----------------
// MODE 0: plain store. MODE 1 (QKV): fused epilogue —
//   q cols (<2048):   RoPE on fp32 acc, pre-scale 0.125*log2(e), bf16 store
//   k cols (<2560):   RoPE on fp32 acc, bf16 store
//   v cols (>=2560):  no rope; store transposed into vt[(b*8+kv)*64+d][T]
template <typename OutT, int MODE>
__global__ __launch_bounds__(256, 3)
void gemm_bt(const bf16_t* __restrict__ A, const bf16_t* __restrict__ Bt,
             OutT* __restrict__ C, int M, int N, int K, bf16_t* __restrict__ vt) {
  __shared__ __align__(16) bf16_t As[128 * 64];
  __shared__ __align__(16) bf16_t Bs[128 * 64];
  const int tid = threadIdx.x;
  const int wave = tid >> 6, lane = tid & 63, g = lane >> 4, l15 = lane & 15;
  // ---- XCD-chunked remap (T1): XCD = L&7 owns a contiguous by-stripe ----
  // (requires gridDim.y % 8 == 0: 32 for both launches)
  const int Lg = blockIdx.x + gridDim.x * blockIdx.y;
  const int cx = Lg & 7, rr = Lg >> 3;
  const int bxr = rr % gridDim.x;
  const int byr = cx * (gridDim.y >> 3) + rr / gridDim.x;
  const int m0 = byr * 128, n0 = bxr * 128;
  const int mw = (wave >> 1) * 64, nw = (wave & 1) * 64;
  const bf16_t* Ab = A + (long)m0 * K;
  const bf16_t* Bb = Bt + (long)n0 * K;
  f32x4 acc[4][4] = {};
  const int nkt = K >> 6;
  for (int kt = 0; kt < nkt; ++kt) {
    __syncthreads();
#pragma unroll
    for (int i = 0; i < 4; ++i) {
      int c = i * 256 + tid;
      int row = c >> 3, pos = c & 7;
      int gcol = ((pos ^ (row & 7)) * 8);
      gload_lds16(Ab + (long)row * K + kt * 64 + gcol, &As[c * 8]);
      gload_lds16(Bb + (long)row * K + kt * 64 + gcol, &Bs[c * 8]);
    }
    __syncthreads();
#pragma unroll
    for (int ks = 0; ks < 2; ++ks) {
      bf16x8 af[4], bq[4];
#pragma unroll
      for (int i = 0; i < 4; ++i) {
        int pos = ((ks * 4 + g) ^ (l15 & 7)) * 8;
        af[i] = *(const bf16x8*)&As[(mw + i * 16 + l15) * 64 + pos];
        bq[i] = *(const bf16x8*)&Bs[(nw + i * 16 + l15) * 64 + pos];
      }
#pragma unroll
      for (int i = 0; i < 4; ++i)
#pragma unroll
        for (int j = 0; j < 4; ++j)
          acc[i][j] = __builtin_amdgcn_mfma_f32_16x16x32_bf16(af[i], bq[j], acc[i][j], 0, 0, 0);
    }
  }

  if (MODE == 1) {
    const int cnb = n0 + nw;                 // wave's head base col (mult of 64)
    if (cnb >= 2560) {
      // ---- V: store transposed into vt[((b*8+kv)*64 + d)*2048 + t] ----
      const int kv = (cnb - 2560) >> 6;
      const int bb = m0 >> 11;
#pragma unroll
      for (int i = 0; i < 4; ++i) {
        const int t0 = (m0 & 2047) + mw + i * 16 + g * 4;
#pragma unroll
        for (int j = 0; j < 4; ++j) {
          const int d = j * 16 + l15;
          bf16_t o4[4];
#pragma unroll
          for (int ii = 0; ii < 4; ++ii) o4[ii] = __float2bfloat16(acc[i][j][ii]);
          *(ushort4*)&vt[((long)((bb * 8 + kv) * 64 + d)) * 2048 + t0] = *(ushort4*)o4;
        }
      }
    } else {
      // ---- Q/K: RoPE in-register (pair (d, d+32) = acc[i][jp] / acc[i][jp+2]) ----
      const float sc = (cnb < 2048) ? 0.18033688011112043f : 1.0f;  // 0.125*log2(e) for q
#pragma unroll
      for (int jp = 0; jp < 2; ++jp) {
        const int d = jp * 16 + l15;
        const float invf = exp2f(-(float)d * 0.4152410118074032f);  // log2(10000)/32
        const int cn = cnb + jp * 16 + l15;
#pragma unroll
        for (int i = 0; i < 4; ++i) {
          const int r0 = m0 + mw + i * 16 + g * 4;
#pragma unroll
          for (int ii = 0; ii < 4; ++ii) {
            const int t = (r0 + ii) & 2047;
            float ang = (float)t * invf;
            float rev = ang * 0.15915494309189535f;
            float fr = (rev - rintf(rev)) * 6.283185307179586f;  // [-pi, pi]
            float sv = __sinf(fr), cv = __cosf(fr);
            float x1 = acc[i][jp][ii], x2 = acc[i][jp + 2][ii];
            store_out(&C[(long)(r0 + ii) * N + cn],      (x1 * cv - x2 * sv) * sc);
            store_out(&C[(long)(r0 + ii) * N + cn + 32], (x1 * sv + x2 * cv) * sc);
          }
        }
      }
    }
  } else {
#pragma unroll
    for (int i = 0; i < 4; ++i)
#pragma unroll
      for (int j = 0; j < 4; ++j) {
        int r = m0 + mw + i * 16 + g * 4;
        int cn = n0 + nw + j * 16 + l15;
#pragma unroll
        for (int ii = 0; ii < 4; ++ii)
          store_out(&C[(long)(r + ii) * N + cn], acc[i][j][ii]);
      }
  }
}

// ---------------- Flash attention: 64-key tiles, dbuf, XCD-local K/V, CU-balanced ----------------
// Block remap: each XCD owns 2 (b,kvh) pairs -> K/V panels L2-resident;
// same-CU blocks alternate qt/15-qt -> 68 tiles/CU.
// LDS: Ks 2x8K + Vs 2x8K = 32768 B. P stays in registers (permlane relayout).
__global__ __launch_bounds__(256, 4)
void flash_attn(const bf16_t* __restrict__ qkv, const bf16_t* __restrict__ vt,
                bf16_t* __restrict__ y) {
  constexpr int T = 2048, LDQ = 3072;
  __shared__ __align__(16) bf16_t Ks[2][64 * 64];   // [kk][d], chunk-swizzled
  __shared__ __align__(16) bf16_t Vs[2][64 * 64];   // [d][kk], chunk-swizzled
  const int tid = threadIdx.x, wave = tid >> 6, lane = tid & 63, g = lane >> 4, l15 = lane & 15;
  // ---- XCD-aware decode ----
  const int L = blockIdx.x + (blockIdx.y << 4) + (blockIdx.z << 9);
  const int c = L & 7, s = L >> 3;
  const int t8 = s & 31, u = s >> 5;
  const int p = c * 2 + (t8 & 1);      // b*8 + kvh
  const int b = p >> 3, kvh = p & 7;
  const int h = kvh * 4 + u;           // q-head within the kv group
  const int j0 = t8 >> 1;
  const int qt0 = (j0 < 8) ? (15 - j0) : (j0 - 8);
  const int qt = (u & 1) ? (15 - qt0) : qt0;   // per-CU balance
  const bf16_t* qbase = qkv + (long)(b * T + qt * 128) * LDQ + h * 64;
  const bf16_t* kbase = qkv + (long)(b * T) * LDQ + 2048 + kvh * 64;
  const bf16_t* vbase = vt + (long)((b * 8 + kvh) * 64) * T;

  // Q fragments (B-operand layout: n=q=l15, kdim=g*8+jj)
  bf16x8 qf[2][2];
#pragma unroll
  for (int ms = 0; ms < 2; ++ms)
#pragma unroll
    for (int hh = 0; hh < 2; ++hh)
      qf[ms][hh] = *(const bf16x8*)(qbase + (long)(wave * 32 + ms * 16 + l15) * LDQ + hh * 32 + g * 8);

  bf16x8 onef;
#pragma unroll
  for (int i = 0; i < 8; ++i) onef[i] = (__bf16)1.0f;

  f32x4 o[2][4] = {};
  f32x4 lacc[2] = {};
  const f32x4 fz = {0.f, 0.f, 0.f, 0.f};

  // hoisted staging addresses: c = i*256+tid, i in {0,1}
  const int c0 = tid, c1 = 256 + tid;
  const int row0 = c0 >> 3, pos0 = c0 & 7, sw0 = ((pos0 ^ (row0 & 7)) * 8);
  const int row1 = c1 >> 3, pos1 = c1 & 7, sw1 = ((pos1 ^ (row1 & 7)) * 8);
  const bf16_t* kp0 = kbase + (long)row0 * LDQ + sw0;
  const bf16_t* kp1 = kbase + (long)row1 * LDQ + sw1;
  const bf16_t* vp0 = vbase + (long)row0 * T + sw0;
  const bf16_t* vp1 = vbase + (long)row1 * T + sw1;
  const int l0 = c0 * 8, l1 = c1 * 8;

  auto stage = [&](int buf) {
    gload_lds16(kp0, &Ks[buf][l0]);
    gload_lds16(vp0, &Vs[buf][l0]);
    gload_lds16(kp1, &Ks[buf][l1]);
    gload_lds16(vp1, &Vs[buf][l1]);
    kp0 += 64 * LDQ; kp1 += 64 * LDQ;
    vp0 += 64;       vp1 += 64;
  };

  stage(0);
  const int nkt = 2 * qt + 2;
  for (int kt = 0; kt < nkt; ++kt) {
    __syncthreads();               // vmcnt(0) drain precedes barrier: buf[kt&1] ready
    if (kt + 1 < nkt) stage((kt + 1) & 1);
    const bf16_t* Kc = Ks[kt & 1];
    const bf16_t* Vc = Vs[kt & 1];
    const int dk = kt - 2 * qt;        // >=0 only on the two diagonal tiles
    const bool diag = (dk >= 0);

#pragma unroll
    for (int ks = 0; ks < 2; ++ks) {
      // ---- S^T chunk: rows k = ks*32 + nsl*16 + g*4+ii, cols q = l15 ----
      f32x4 s2[2][2];
      __builtin_amdgcn_s_setprio(1);
#pragma unroll
      for (int nsl = 0; nsl < 2; ++nsl) {
        int krow = ks * 32 + nsl * 16 + l15;
        bf16x8 kf0 = *(const bf16x8*)&Kc[krow * 64 + ((g ^ (l15 & 7)) * 8)];
        bf16x8 kf1 = *(const bf16x8*)&Kc[krow * 64 + (((4 + g) ^ (l15 & 7)) * 8)];
#pragma unroll
        for (int ms = 0; ms < 2; ++ms) {
          f32x4 tt = __builtin_amdgcn_mfma_f32_16x16x32_bf16(kf0, qf[ms][0], fz, 0, 0, 0);
          s2[ms][nsl] = __builtin_amdgcn_mfma_f32_16x16x32_bf16(kf1, qf[ms][1], tt, 0, 0, 0);
        }
      }
      __builtin_amdgcn_s_setprio(0);
      // ---- P = exp2(S) (q pre-scaled), mask, cvt_pk pack, permlane relayout ----
      // S^T regs: lane(g,l15) nsl,ii -> P[q=l15(+ms*16)][k = nsl*16+g*4+ii]
      // A-frag:   lane(g,l15) jj     -> P[q=l15(+ms*16)][k = g*8+jj]
      bf16x8 pf[2];
#pragma unroll
      for (int ms = 0; ms < 2; ++ms) {
        unsigned dw[4];
#pragma unroll
        for (int nsl = 0; nsl < 2; ++nsl) {
          float pp[4];
#pragma unroll
          for (int ii = 0; ii < 4; ++ii) {
            float pv = fast_exp2(s2[ms][nsl][ii]);
            if (diag && (dk * 64 + ks * 32 + nsl * 16 + g * 4 + ii >
                         wave * 32 + ms * 16 + l15)) pv = 0.f;
            pp[ii] = pv;
          }
          dw[nsl * 2 + 0] = cvt_pk_bf16(pp[0], pp[1]);   // k = nsl*16+g*4 + {0,1}
          dw[nsl * 2 + 1] = cvt_pk_bf16(pp[2], pp[3]);   // k = nsl*16+g*4 + {2,3}
        }
        // rows(g) of dw[0],dw[2]: [S0g0..] / [S2g0..]; after 32swap+16swap:
        // dw[0] = [S0g0 S0g2 S2g0 S2g2] = w0, dw[2] = [S0g1 S0g3 S2g1 S2g3] = w2
        permlane32_swap(dw[0], dw[2]);
        permlane16_swap(dw[0], dw[2]);
        permlane32_swap(dw[1], dw[3]);
        permlane16_swap(dw[1], dw[3]);
        uint4 uu = {dw[0], dw[1], dw[2], dw[3]};
        pf[ms] = __builtin_bit_cast(bf16x8, uu);
        lacc[ms] = __builtin_amdgcn_mfma_f32_16x16x32_bf16(pf[ms], onef, lacc[ms], 0, 0, 0);
      }
      // ---- PV chunk ----
      __builtin_amdgcn_s_setprio(1);
#pragma unroll
      for (int ds = 0; ds < 4; ++ds) {
        bf16x8 vf = *(const bf16x8*)&Vc[(ds * 16 + l15) * 64 + (((ks * 4 + g) ^ (l15 & 7)) * 8)];
        o[0][ds] = __builtin_amdgcn_mfma_f32_16x16x32_bf16(pf[0], vf, o[0][ds], 0, 0, 0);
        o[1][ds] = __builtin_amdgcn_mfma_f32_16x16x32_bf16(pf[1], vf, o[1][ds], 0, 0, 0);
      }
      __builtin_amdgcn_s_setprio(0);
    }
  }

  // ---- epilogue: normalize, transpose 16x64 halves via LDS (reuse Vs), b128 stores ----
  __syncthreads();                         // all waves done reading Ks/Vs
  bf16_t* E = (bf16_t*)&Vs[0][0] + wave * 1152;  // 16*72 = 1152 per wave
#pragma unroll
  for (int ms = 0; ms < 2; ++ms) {
    f32x4 linv;
#pragma unroll
    for (int ii = 0; ii < 4; ++ii) linv[ii] = 1.0f / lacc[ms][ii];
#pragma unroll
    for (int ds = 0; ds < 4; ++ds)
#pragma unroll
      for (int ii = 0; ii < 4; ++ii)
        E[(g * 4 + ii) * 72 + ds * 16 + l15] = __float2bfloat16(o[ms][ds][ii] * linv[ii]);
    // wave-private region, in-order DS ops -> no barrier
    bf16x8 r0 = *(const bf16x8*)&E[l15 * 72 + g * 16];
    bf16x8 r1 = *(const bf16x8*)&E[l15 * 72 + g * 16 + 8];
    int q = qt * 128 + wave * 32 + ms * 16 + l15;
    *(bf16x8*)&y[(long)(b * T + q) * 2048 + h * 64 + g * 16] = r0;
    *(bf16x8*)&y[(long)(b * T + q) * 2048 + h * 64 + g * 16 + 8] = r1;
  }
}

extern "C" void kernel_launch(void* const* d_in, const int* in_sizes, int n_in,
                              void* d_out, int out_size, void* d_ws, size_t ws_size,
                              hipStream_t stream) {
  const float* x  = (const float*)d_in[0];
  const float* Wq = (const float*)d_in[1];
  const float* Wk = (const float*)d_in[2];
  const float* Wv = (const float*)d_in[3];
  const float* Wo = (const float*)d_in[4];
  float* out = (float*)d_out;
  char* ws = (char*)d_ws;

  bf16_t* xb    = (bf16_t*)(ws);                                     // 16.78 MB (reused as y)
  bf16_t* wqkvt = (bf16_t*)(ws + 16777216);                          // 12.58 MB
  bf16_t* wot   = (bf16_t*)(ws + 16777216 + 12582912);               // 8.39 MB
  bf16_t* qkvb  = (bf16_t*)(ws + 16777216 + 12582912 + 8388608);     // 25.17 MB
  bf16_t* vtb   = (bf16_t*)(ws + 16777216 + 12582912 + 8388608 + 25165824); // 4.19 MB
  bf16_t* yb = xb;  // x dead after QKV GEMM

  prep<<<12288, 256, 0, stream>>>(x, Wq, Wk, Wv, Wo, xb, wqkvt, wot);
  gemm_bt<bf16_t, 1><<<dim3(24, 32), 256, 0, stream>>>(xb, wqkvt, qkvb, 4096, 3072, 2048, vtb);
  flash_attn<<<dim3(16, 32, 2), 256, 0, stream>>>(qkvb, vtb, yb);
  gemm_bt<float, 0><<<dim3(16, 32), 256, 0, stream>>>(yb, wot, out, 4096, 2048, 2048, nullptr);
}